// Round 3
// baseline (927.713 us; speedup 1.0000x reference)
//
#include <hip/hip_runtime.h>

#define B_   8
#define D_   256
#define T_   4096
#define NQ_  8
#define K_   1024

#define IDX_OFF  ((size_t)B_ * T_ * D_)             // 8388608
#define LOSS_OFF (IDX_OFF + (size_t)NQ_ * B_ * T_)  // 8650752

// ---- workspace layout (bytes) ----
#define XT_OFF   0ull                      // float xT[32768][256] (32 MB)
#define CB16_OFF 33554432ull               // fp16 codebook in MFMA A-frag order (4 MB)
#define CN_OFF   37748736ull               // float cnorm[8192]
#define LB_OFF   37781504ull               // double lossbuf[8]

typedef _Float16 half8 __attribute__((ext_vector_type(8)));   // 4 VGPR MFMA frag
typedef float   f32x16 __attribute__((ext_vector_type(16)));  // MFMA C/D

__device__ __forceinline__ ushort f2h(float f) {
  return __builtin_bit_cast(ushort, (_Float16)f);
}

// packed score: low 10 mantissa bits replaced by code -> branch-free sorted-top-3 via min/max net
__device__ __forceinline__ float packsc(float sc, uint code) {
  return __builtin_bit_cast(float, (__builtin_bit_cast(uint, sc) & ~1023u) | code);
}
__device__ __forceinline__ void ins3(float& v1, float& v2, float& v3, float f) {
  const float a1 = fminf(v1, f), b1 = fmaxf(v1, f);
  v1 = a1;
  const float a2 = fminf(v2, b1), b2 = fmaxf(v2, b1);
  v2 = a2;
  v3 = fminf(v3, b2);
}

// ---- prep 1: x [B,D,T] -> xT f32 [row=b*T+t][d] ----
__global__ void prep_xT(const float* __restrict__ x, float* __restrict__ xT) {
  __shared__ float tile[64][65];
  const int bidx = blockIdx.x;                 // 8 b * 4 dchunk * 64 tchunk
  const int b = bidx >> 8, dc = (bidx >> 6) & 3, tc = bidx & 63;
  const int d0 = dc * 64, t0 = tc * 64;
  const int tid = threadIdx.x;
  {
    const int tt = tid & 63, dg = tid >> 6;
    for (int i = 0; i < 16; ++i) {
      const int d = dg * 16 + i;
      tile[d][tt] = x[((size_t)(b * D_ + d0 + d)) * T_ + t0 + tt];
    }
  }
  __syncthreads();
  {
    const int dw = tid & 63, tg = tid >> 6;
    for (int i = 0; i < 16; ++i) {
      const int t = tg * 16 + i;
      xT[((size_t)b * T_ + t0 + t) * D_ + d0 + dw] = tile[dw][t];
    }
  }
}

// ---- prep 2: cb f32 -> fp16 MFMA A-frag order + f64-accurate cnorm (f32 out) ----
// layout: cb16[stage][tile(code>>5)][ks(k>>4)][lane][8]; lane = ((k>>3)&1)*32 + (code&31), j=k&7
__global__ void prep_cb16(const float* __restrict__ cb, ushort* __restrict__ cb16,
                          float* __restrict__ cnorm) {
  const int tid = threadIdx.x, w = tid >> 6, l = tid & 63;
  const int code = blockIdx.x * 4 + w;         // grid 2048
  const int s = code >> 10, ci = code & 1023, tile = ci >> 5, n = ci & 31;
  const float* row = cb + (size_t)code * D_;
  const float4 v = *(const float4*)(row + l * 4);
  double nrm = (double)v.x * v.x + (double)v.y * v.y + (double)v.z * v.z + (double)v.w * v.w;
  ushort4 p;
  p.x = f2h(v.x); p.y = f2h(v.y); p.z = f2h(v.z); p.w = f2h(v.w);
  const int ks = l >> 2, lf = ((l >> 1) & 1) * 32 + n, j0 = (l & 1) * 4;
  const size_t off = (((size_t)s * 32 + tile) * 16 + ks) * 512 + (size_t)lf * 8 + j0;
  *(ushort4*)(cb16 + off) = p;
#pragma unroll
  for (int m = 1; m <= 32; m <<= 1) nrm += __shfl_xor(nrm, m);
  if (l == 0) cnorm[code] = (float)nrm;
}

// ---- main: 1024 blocks x 256 thr; block = 32 rows; wave w = codes w*256..+255 (8 tiles) ----
// Residual storage split by role:
//   * exact residual (double-single hi+lo): 64 REGISTERS per thread (thread owns row=tid>>3,
//     dims (tid&7)*32..+31 -- mapping is stage-invariant).
//   * scoring residual: fp16 in LDS, ALREADY in MFMA B-frag layout (16 KB, XOR-swizzled).
//     Phase 3 writes it via cvt_pkrtz; B-build is 16 clean ds_read_b128, zero conversion.
// LDS ~17.9 KB; persistent regs ~ b(64)+hi(32)+lo(32)+misc -> ~145 arch + 16 acc.
// waves_per_eu(3): unified-file cap ~170 -> 3 waves/SIMD, no scratch.
// res16 granule index: g = kb*32 + (n5 ^ ((kb>>2)&7)), kb = k>>3 (dim-block), n5 = row.
__attribute__((amdgpu_waves_per_eu(3)))
__global__ __launch_bounds__(256)
void rvq_main(const float* __restrict__ cb, const float* __restrict__ xT,
              const ushort* __restrict__ cb16, const float* __restrict__ cnorm,
              float* __restrict__ out, double* __restrict__ lossbuf) {
  __shared__ __align__(16) uint4  res16[1024];      // 16 KB fp16 residual, B-frag layout
  __shared__ float candm[32][12];                   // packed score|code, 1.5 KB

  const int tid = threadIdx.x;
  const int w = tid >> 6, l = tid & 63, n5 = l & 31, h = l >> 5;
  const size_t row0 = (size_t)blockIdx.x * 32;
  const int rowL = tid >> 3;            // phase-3 row  (== w*8 + (l>>3))
  const int dq = tid & 7;               // phase-3 dim-octant (32 dims)

  float hi[4][8];                       // residual high part, register-resident
  float lo[4][8];                       // residual low part (double-single)

  // ---- init: residual = (x, 0); write fp16 frag image ----
  {
#pragma unroll
    for (int cc = 0; cc < 4; ++cc) {
      const int kb = dq * 4 + cc;
      const float* xp = xT + (row0 + rowL) * D_ + kb * 8;
      const float4 x0 = *(const float4*)xp, x1 = *(const float4*)(xp + 4);
      hi[cc][0] = x0.x; hi[cc][1] = x0.y; hi[cc][2] = x0.z; hi[cc][3] = x0.w;
      hi[cc][4] = x1.x; hi[cc][5] = x1.y; hi[cc][6] = x1.z; hi[cc][7] = x1.w;
#pragma unroll
      for (int j = 0; j < 8; ++j) lo[cc][j] = 0.0f;
      uint4 pv;
      pv.x = __builtin_bit_cast(uint, __builtin_amdgcn_cvt_pkrtz(x0.x, x0.y));
      pv.y = __builtin_bit_cast(uint, __builtin_amdgcn_cvt_pkrtz(x0.z, x0.w));
      pv.z = __builtin_bit_cast(uint, __builtin_amdgcn_cvt_pkrtz(x1.x, x1.y));
      pv.w = __builtin_bit_cast(uint, __builtin_amdgcn_cvt_pkrtz(x1.z, x1.w));
      res16[kb * 32 + (rowL ^ dq)] = pv;           // (kb>>2)&7 == dq
    }
  }
  __syncthreads();

  for (int s = 0; s < NQ_; ++s) {
    // ===== B fragments: 16 ds_read_b128, no conversion =====
    half8 b[16];
#pragma unroll
    for (int ks = 0; ks < 16; ++ks) {
      const uint4 bv = res16[(ks * 2 + h) * 32 + (n5 ^ ((ks >> 1) & 7))];
      b[ks] = __builtin_bit_cast(half8, bv);
    }

    // ===== K-loop: 8 tiles x 16 MFMAs; two independent top-3 chains (even/odd rr) =====
    float v1 = 3e38f, v2 = 3e38f, v3 = 3e38f;   // chain A
    float u1 = 3e38f, u2 = 3e38f, u3 = 3e38f;   // chain B
    for (int tt = 0; tt < 8; ++tt) {
      const int t = w * 8 + tt;
      const uint4* ap = (const uint4*)(cb16 + ((size_t)(s * 32 + t) * 16) * 512) + l;
      f32x16 acc;
#pragma unroll
      for (int r = 0; r < 16; ++r) acc[r] = 0.0f;
#pragma unroll
      for (int ks = 0; ks < 16; ++ks) {
        const uint4 av = ap[(size_t)ks * 64];
        acc = __builtin_amdgcn_mfma_f32_32x32x16_f16(__builtin_bit_cast(half8, av), b[ks], acc, 0, 0, 0);
      }
      const float* cnb = cnorm + s * K_ + t * 32 + h * 4;
      const uint cbase = (uint)(t * 32 + 4 * h);
#pragma unroll
      for (int q = 0; q < 4; ++q) {                      // quarter-split keeps cna regs low
        const float4 cq = *(const float4*)(cnb + q * 8);
        const float cna[4] = {cq.x, cq.y, cq.z, cq.w};
#pragma unroll
        for (int rr = 0; rr < 4; ++rr) {
          const int r = q * 4 + rr;
          const float sc = cna[rr] - 2.0f * acc[r];
          const uint code = cbase + (uint)(8 * q + rr);  // == t*32 + (r&3) + 8*(r>>2) + 4*h
          const float f = packsc(sc, code);
          if (rr & 1) ins3(u1, u2, u3, f);
          else        ins3(v1, v2, v3, f);
        }
      }
    }
    // merge chain B into chain A
    ins3(v1, v2, v3, u1);
    ins3(v1, v2, v3, u2);
    ins3(v1, v2, v3, u3);
    // merge h-halves (lane l <-> l^32, same x-row, disjoint codes)
    {
      const float o1 = __shfl_xor(v1, 32), o2 = __shfl_xor(v2, 32), o3 = __shfl_xor(v3, 32);
      ins3(v1, v2, v3, o1);
      ins3(v1, v2, v3, o2);
      ins3(v1, v2, v3, o3);
    }
    if (h == 0) {
      candm[n5][w * 3 + 0] = v1;
      candm[n5][w * 3 + 1] = v2;
      candm[n5][w * 3 + 2] = v3;
    }
    __syncthreads();

    // ===== phase 3: 8 lanes/row x 32 dims; f64 re-eval of top-3-of-12 (regs-only residual) =====
    double lossW = 0.0;
    {
      float m1 = 3e38f, m2 = 3e38f, m3 = 3e38f;
#pragma unroll
      for (int cd = 0; cd < 12; ++cd) ins3(m1, m2, m3, candm[rowL][cd]);
      const int c1 = (int)(__builtin_bit_cast(uint, m1) & 1023u);
      const int c2 = (int)(__builtin_bit_cast(uint, m2) & 1023u);
      const int c3 = (int)(__builtin_bit_cast(uint, m3) & 1023u);

      const float* cbs = cb + (size_t)s * K_ * D_;
      const float* cr0 = cbs + (size_t)c1 * D_;
      const float* cr1 = cbs + (size_t)c2 * D_;
      const float* cr2 = cbs + (size_t)c3 * D_;
      double dd0 = 0.0, dd1 = 0.0, dd2 = 0.0;
#pragma unroll
      for (int cc = 0; cc < 4; ++cc) {
        const int kb = dq * 4 + cc;
        const int go = kb * 8;
        const float4 a0 = *(const float4*)(cr0 + go), a1 = *(const float4*)(cr0 + go + 4);
        const float4 b0 = *(const float4*)(cr1 + go), b1 = *(const float4*)(cr1 + go + 4);
        const float4 g0 = *(const float4*)(cr2 + go), g1 = *(const float4*)(cr2 + go + 4);
        const float af[8] = {a0.x, a0.y, a0.z, a0.w, a1.x, a1.y, a1.z, a1.w};
        const float bf[8] = {b0.x, b0.y, b0.z, b0.w, b1.x, b1.y, b1.z, b1.w};
        const float gf[8] = {g0.x, g0.y, g0.z, g0.w, g1.x, g1.y, g1.z, g1.w};
#pragma unroll
        for (int j = 0; j < 8; ++j) {
          const double r64 = (double)hi[cc][j] + (double)lo[cc][j];
          const double u = r64 - (double)af[j]; dd0 += u * u;
          const double v = r64 - (double)bf[j]; dd1 += v * v;
          const double g = r64 - (double)gf[j]; dd2 += g * g;
        }
      }
#pragma unroll
      for (int m = 1; m <= 4; m <<= 1) {
        dd0 += __shfl_xor(dd0, m); dd1 += __shfl_xor(dd1, m); dd2 += __shfl_xor(dd2, m);
      }
      int win = c1; double dwn = dd0;
      if (dd1 < dwn || (dd1 == dwn && c2 < win)) { win = c2; dwn = dd1; }
      if (dd2 < dwn || (dd2 == dwn && c3 < win)) { win = c3; dwn = dd2; }
      const float* crw = cbs + (size_t)win * D_;
#pragma unroll
      for (int cc = 0; cc < 4; ++cc) {
        const int kb = dq * 4 + cc;
        const int go = kb * 8;
        const float4 w0 = *(const float4*)(crw + go), w1 = *(const float4*)(crw + go + 4);
        const float wf[8] = {w0.x, w0.y, w0.z, w0.w, w1.x, w1.y, w1.z, w1.w};
        double n64[8];
#pragma unroll
        for (int j = 0; j < 8; ++j)
          n64[j] = ((double)hi[cc][j] + (double)lo[cc][j]) - (double)wf[j];
        if (s < NQ_ - 1) {
#pragma unroll
          for (int j = 0; j < 8; ++j) {
            hi[cc][j] = (float)n64[j];
            lo[cc][j] = (float)(n64[j] - (double)hi[cc][j]);
          }
          uint4 pv;
          pv.x = __builtin_bit_cast(uint, __builtin_amdgcn_cvt_pkrtz(hi[cc][0], hi[cc][1]));
          pv.y = __builtin_bit_cast(uint, __builtin_amdgcn_cvt_pkrtz(hi[cc][2], hi[cc][3]));
          pv.z = __builtin_bit_cast(uint, __builtin_amdgcn_cvt_pkrtz(hi[cc][4], hi[cc][5]));
          pv.w = __builtin_bit_cast(uint, __builtin_amdgcn_cvt_pkrtz(hi[cc][6], hi[cc][7]));
          res16[kb * 32 + (rowL ^ dq)] = pv;
        } else {
          const float* xp = xT + (row0 + rowL) * D_ + go;
          const float4 x0 = *(const float4*)xp, x1 = *(const float4*)(xp + 4);
          float o[8];
          o[0] = (float)((double)x0.x - n64[0]); o[1] = (float)((double)x0.y - n64[1]);
          o[2] = (float)((double)x0.z - n64[2]); o[3] = (float)((double)x0.w - n64[3]);
          o[4] = (float)((double)x1.x - n64[4]); o[5] = (float)((double)x1.y - n64[5]);
          o[6] = (float)((double)x1.z - n64[6]); o[7] = (float)((double)x1.w - n64[7]);
          float* od = out + (row0 + rowL) * D_ + go;
          *(float4*)od       = make_float4(o[0], o[1], o[2], o[3]);
          *(float4*)(od + 4) = make_float4(o[4], o[5], o[6], o[7]);
        }
      }
      if (dq == 0) {
        out[IDX_OFF + (size_t)s * (B_ * T_) + row0 + rowL] = (float)win;
        lossW = dwn;
      }
    }
    // lossW nonzero only on lanes with dq==0 (l % 8 == 0): masks 8/16/32 suffice
#pragma unroll
    for (int m = 8; m <= 32; m <<= 1) lossW += __shfl_xor(lossW, m);
    if (l == 0) atomicAdd(&lossbuf[s], lossW);
    __syncthreads();
  }
}

__global__ void rvq_loss(const double* __restrict__ lossbuf, float* __restrict__ out) {
  const int s = threadIdx.x;
  if (s < NQ_) out[LOSS_OFF + s] = (float)(2.0 * lossbuf[s] / (double)((size_t)B_ * T_ * D_));
}

extern "C" void kernel_launch(void* const* d_in, const int* in_sizes, int n_in,
                              void* d_out, int out_size, void* d_ws, size_t ws_size,
                              hipStream_t stream) {
  const float* x  = (const float*)d_in[0];   // [B, D, T] f32
  const float* cb = (const float*)d_in[1];   // [NQ, K, D] f32
  float* out = (float*)d_out;
  char* ws = (char*)d_ws;
  float*  xTp   = (float*)(ws + XT_OFF);
  ushort* cb16p = (ushort*)(ws + CB16_OFF);
  float*  cnp   = (float*)(ws + CN_OFF);
  double* lbp   = (double*)(ws + LB_OFF);

  hipMemsetAsync(ws + LB_OFF, 0, NQ_ * sizeof(double), stream);
  prep_xT<<<2048, 256, 0, stream>>>(x, xTp);
  prep_cb16<<<2048, 256, 0, stream>>>(cb, cb16p, cnp);
  rvq_main<<<1024, 256, 0, stream>>>(cb, xTp, cb16p, cnp, out, lbp);
  rvq_loss<<<1, 64, 0, stream>>>(lbp, out);
}

// Round 4
// 590.528 us; speedup vs baseline: 1.5710x; 1.5710x over previous
//
#include <hip/hip_runtime.h>

#define B_   8
#define D_   256
#define T_   4096
#define NQ_  8
#define K_   1024

#define IDX_OFF  ((size_t)B_ * T_ * D_)             // 8388608
#define LOSS_OFF (IDX_OFF + (size_t)NQ_ * B_ * T_)  // 8650752

// ---- workspace layout (bytes) ----
#define XT_OFF   0ull                      // float xT[32768][256] (32 MB)
#define CB16_OFF 33554432ull               // fp16 codebook in MFMA A-frag order (4 MB)
#define CN_OFF   37748736ull               // float cnorm[8192]
#define LB_OFF   37781504ull               // double lossbuf[8]

typedef _Float16 half8 __attribute__((ext_vector_type(8)));   // 4 VGPR MFMA frag
typedef float   f32x16 __attribute__((ext_vector_type(16)));  // MFMA C/D

__device__ __forceinline__ ushort f2h(float f) {
  return __builtin_bit_cast(ushort, (_Float16)f);
}

// packed score: low 10 mantissa bits replaced by code -> branch-free sorted-top-3 via min/max net
__device__ __forceinline__ float packsc(float sc, uint code) {
  return __builtin_bit_cast(float, (__builtin_bit_cast(uint, sc) & ~1023u) | code);
}
__device__ __forceinline__ void ins3(float& v1, float& v2, float& v3, float f) {
  const float a1 = fminf(v1, f), b1 = fmaxf(v1, f);
  v1 = a1;
  const float a2 = fminf(v2, b1), b2 = fmaxf(v2, b1);
  v2 = a2;
  v3 = fminf(v3, b2);
}

// ---- prep 1: x [B,D,T] -> xT f32 [row=b*T+t][d] ----
__global__ void prep_xT(const float* __restrict__ x, float* __restrict__ xT) {
  __shared__ float tile[64][65];
  const int bidx = blockIdx.x;                 // 8 b * 4 dchunk * 64 tchunk
  const int b = bidx >> 8, dc = (bidx >> 6) & 3, tc = bidx & 63;
  const int d0 = dc * 64, t0 = tc * 64;
  const int tid = threadIdx.x;
  {
    const int tt = tid & 63, dg = tid >> 6;
    for (int i = 0; i < 16; ++i) {
      const int d = dg * 16 + i;
      tile[d][tt] = x[((size_t)(b * D_ + d0 + d)) * T_ + t0 + tt];
    }
  }
  __syncthreads();
  {
    const int dw = tid & 63, tg = tid >> 6;
    for (int i = 0; i < 16; ++i) {
      const int t = tg * 16 + i;
      xT[((size_t)b * T_ + t0 + t) * D_ + d0 + dw] = tile[dw][t];
    }
  }
}

// ---- prep 2: cb f32 -> fp16 MFMA A-frag order + f64-accurate cnorm (f32 out) ----
// layout: cb16[stage][tile(code>>5)][ks(k>>4)][lane][8]; lane = ((k>>3)&1)*32 + (code&31), j=k&7
__global__ void prep_cb16(const float* __restrict__ cb, ushort* __restrict__ cb16,
                          float* __restrict__ cnorm) {
  const int tid = threadIdx.x, w = tid >> 6, l = tid & 63;
  const int code = blockIdx.x * 4 + w;         // grid 2048
  const int s = code >> 10, ci = code & 1023, tile = ci >> 5, n = ci & 31;
  const float* row = cb + (size_t)code * D_;
  const float4 v = *(const float4*)(row + l * 4);
  double nrm = (double)v.x * v.x + (double)v.y * v.y + (double)v.z * v.z + (double)v.w * v.w;
  ushort4 p;
  p.x = f2h(v.x); p.y = f2h(v.y); p.z = f2h(v.z); p.w = f2h(v.w);
  const int ks = l >> 2, lf = ((l >> 1) & 1) * 32 + n, j0 = (l & 1) * 4;
  const size_t off = (((size_t)s * 32 + tile) * 16 + ks) * 512 + (size_t)lf * 8 + j0;
  *(ushort4*)(cb16 + off) = p;
#pragma unroll
  for (int m = 1; m <= 32; m <<= 1) nrm += __shfl_xor(nrm, m);
  if (l == 0) cnorm[code] = (float)nrm;
}

// ---- main: 1024 blocks x 256 thr; block = 32 rows; wave w = codes w*256..+255 (8 tiles) ----
// Live-set reduction (rounds 1-3 showed any waves_per_eu hint -> allocator clamp -> spills):
//   * B fragments are NOT register-resident: per tile, 16 ds_read_b128 from res16 (already in
//     MFMA B-frag layout). Opaque-zero asm inside the tt loop defeats LICM re-hoisting.
//   * residual is PURE F32 in 32 regs (reference computes res - q in f32; double-single dropped).
//     f64 is still used for the top-3 re-eval distances and the loss.
// Persistent regs ~ res(32) + acc(16) + transients(~44) + misc -> natural alloc ~100-120,
// no attribute: 4 waves/SIMD (grid caps at 4 blocks/CU * 4 waves = 50% occ).
__global__ __launch_bounds__(256)
void rvq_main(const float* __restrict__ cb, const float* __restrict__ xT,
              const ushort* __restrict__ cb16, const float* __restrict__ cnorm,
              float* __restrict__ out, double* __restrict__ lossbuf) {
  __shared__ __align__(16) uint4  res16[1024];      // 16 KB fp16 residual, B-frag layout
  __shared__ float candm[32][12];                   // packed score|code, 1.5 KB

  const int tid = threadIdx.x;
  const int w = tid >> 6, l = tid & 63, n5 = l & 31, h = l >> 5;
  const size_t row0 = (size_t)blockIdx.x * 32;
  const int rowL = tid >> 3;            // phase-3 row  (== w*8 + (l>>3))
  const int dq = tid & 7;               // phase-3 dim-octant (32 dims)

  float res[4][8];                      // f32 residual (reference arithmetic), register-resident

  // ---- init: residual = x; write fp16 frag image ----
  {
#pragma unroll
    for (int cc = 0; cc < 4; ++cc) {
      const int kb = dq * 4 + cc;
      const float* xp = xT + (row0 + rowL) * D_ + kb * 8;
      const float4 x0 = *(const float4*)xp, x1 = *(const float4*)(xp + 4);
      res[cc][0] = x0.x; res[cc][1] = x0.y; res[cc][2] = x0.z; res[cc][3] = x0.w;
      res[cc][4] = x1.x; res[cc][5] = x1.y; res[cc][6] = x1.z; res[cc][7] = x1.w;
      uint4 pv;
      pv.x = __builtin_bit_cast(uint, __builtin_amdgcn_cvt_pkrtz(x0.x, x0.y));
      pv.y = __builtin_bit_cast(uint, __builtin_amdgcn_cvt_pkrtz(x0.z, x0.w));
      pv.z = __builtin_bit_cast(uint, __builtin_amdgcn_cvt_pkrtz(x1.x, x1.y));
      pv.w = __builtin_bit_cast(uint, __builtin_amdgcn_cvt_pkrtz(x1.z, x1.w));
      res16[kb * 32 + (rowL ^ dq)] = pv;           // (kb>>2)&7 == dq
    }
  }
  __syncthreads();

  for (int s = 0; s < NQ_; ++s) {
    // ===== K-loop: 8 tiles; per tile 16 A global-loads + 16 B lds-reads + 16 MFMAs =====
    float v1 = 3e38f, v2 = 3e38f, v3 = 3e38f;   // chain A
    float u1 = 3e38f, u2 = 3e38f, u3 = 3e38f;   // chain B
    for (int tt = 0; tt < 8; ++tt) {
      const int t = w * 8 + tt;
      const uint4* ap = (const uint4*)(cb16 + ((size_t)(s * 32 + t) * 16) * 512) + l;
      int zr = 0;
      asm volatile("" : "+v"(zr));               // opaque 0: B addresses not loop-invariant
      const uint4* bp = res16 + zr;
      f32x16 acc;
#pragma unroll
      for (int r = 0; r < 16; ++r) acc[r] = 0.0f;
#pragma unroll
      for (int q = 0; q < 4; ++q) {              // 4-chunks bound transient reg pressure
        uint4 av[4], bv[4];
#pragma unroll
        for (int c = 0; c < 4; ++c) {
          const int ks = q * 4 + c;
          av[c] = ap[(size_t)ks * 64];
          bv[c] = bp[(ks * 2 + h) * 32 + (n5 ^ ((ks >> 1) & 7))];
        }
#pragma unroll
        for (int c = 0; c < 4; ++c) {
          acc = __builtin_amdgcn_mfma_f32_32x32x16_f16(
              __builtin_bit_cast(half8, av[c]), __builtin_bit_cast(half8, bv[c]), acc, 0, 0, 0);
        }
      }
      const float* cnb = cnorm + s * K_ + t * 32 + h * 4;
      const uint cbase = (uint)(t * 32 + 4 * h);
#pragma unroll
      for (int q = 0; q < 4; ++q) {                      // quarter-split keeps cna regs low
        const float4 cq = *(const float4*)(cnb + q * 8);
        const float cna[4] = {cq.x, cq.y, cq.z, cq.w};
#pragma unroll
        for (int rr = 0; rr < 4; ++rr) {
          const int r = q * 4 + rr;
          const float sc = cna[rr] - 2.0f * acc[r];
          const uint code = cbase + (uint)(8 * q + rr);  // == t*32 + (r&3) + 8*(r>>2) + 4*h
          const float f = packsc(sc, code);
          if (rr & 1) ins3(u1, u2, u3, f);
          else        ins3(v1, v2, v3, f);
        }
      }
    }
    // merge chain B into chain A
    ins3(v1, v2, v3, u1);
    ins3(v1, v2, v3, u2);
    ins3(v1, v2, v3, u3);
    // merge h-halves (lane l <-> l^32, same x-row, disjoint codes)
    {
      const float o1 = __shfl_xor(v1, 32), o2 = __shfl_xor(v2, 32), o3 = __shfl_xor(v3, 32);
      ins3(v1, v2, v3, o1);
      ins3(v1, v2, v3, o2);
      ins3(v1, v2, v3, o3);
    }
    if (h == 0) {
      candm[n5][w * 3 + 0] = v1;
      candm[n5][w * 3 + 1] = v2;
      candm[n5][w * 3 + 2] = v3;
    }
    __syncthreads();   // all K-loop res16 reads done before phase-3 rewrites

    // ===== phase 3: 8 lanes/row x 32 dims; f64 re-eval of top-3-of-12 (f32 residual) =====
    double lossW = 0.0;
    {
      float m1 = 3e38f, m2 = 3e38f, m3 = 3e38f;
#pragma unroll
      for (int cd = 0; cd < 12; ++cd) ins3(m1, m2, m3, candm[rowL][cd]);
      const int c1 = (int)(__builtin_bit_cast(uint, m1) & 1023u);
      const int c2 = (int)(__builtin_bit_cast(uint, m2) & 1023u);
      const int c3 = (int)(__builtin_bit_cast(uint, m3) & 1023u);

      const float* cbs = cb + (size_t)s * K_ * D_;
      const float* cr0 = cbs + (size_t)c1 * D_;
      const float* cr1 = cbs + (size_t)c2 * D_;
      const float* cr2 = cbs + (size_t)c3 * D_;
      double dd0 = 0.0, dd1 = 0.0, dd2 = 0.0;
#pragma unroll
      for (int cc = 0; cc < 4; ++cc) {
        const int kb = dq * 4 + cc;
        const int go = kb * 8;
        const float4 a0 = *(const float4*)(cr0 + go), a1 = *(const float4*)(cr0 + go + 4);
        const float4 b0 = *(const float4*)(cr1 + go), b1 = *(const float4*)(cr1 + go + 4);
        const float4 g0 = *(const float4*)(cr2 + go), g1 = *(const float4*)(cr2 + go + 4);
        const float af[8] = {a0.x, a0.y, a0.z, a0.w, a1.x, a1.y, a1.z, a1.w};
        const float bf[8] = {b0.x, b0.y, b0.z, b0.w, b1.x, b1.y, b1.z, b1.w};
        const float gf[8] = {g0.x, g0.y, g0.z, g0.w, g1.x, g1.y, g1.z, g1.w};
#pragma unroll
        for (int j = 0; j < 8; ++j) {
          const double r64 = (double)res[cc][j];
          const double u = r64 - (double)af[j]; dd0 += u * u;
          const double v = r64 - (double)bf[j]; dd1 += v * v;
          const double g = r64 - (double)gf[j]; dd2 += g * g;
        }
      }
#pragma unroll
      for (int m = 1; m <= 4; m <<= 1) {
        dd0 += __shfl_xor(dd0, m); dd1 += __shfl_xor(dd1, m); dd2 += __shfl_xor(dd2, m);
      }
      int win = c1; double dwn = dd0;
      if (dd1 < dwn || (dd1 == dwn && c2 < win)) { win = c2; dwn = dd1; }
      if (dd2 < dwn || (dd2 == dwn && c3 < win)) { win = c3; dwn = dd2; }
      const float* crw = cbs + (size_t)win * D_;
#pragma unroll
      for (int cc = 0; cc < 4; ++cc) {
        const int kb = dq * 4 + cc;
        const int go = kb * 8;
        const float4 w0 = *(const float4*)(crw + go), w1 = *(const float4*)(crw + go + 4);
        const float wf[8] = {w0.x, w0.y, w0.z, w0.w, w1.x, w1.y, w1.z, w1.w};
        if (s < NQ_ - 1) {
#pragma unroll
          for (int j = 0; j < 8; ++j) res[cc][j] = res[cc][j] - wf[j];   // f32: matches reference
          uint4 pv;
          pv.x = __builtin_bit_cast(uint, __builtin_amdgcn_cvt_pkrtz(res[cc][0], res[cc][1]));
          pv.y = __builtin_bit_cast(uint, __builtin_amdgcn_cvt_pkrtz(res[cc][2], res[cc][3]));
          pv.z = __builtin_bit_cast(uint, __builtin_amdgcn_cvt_pkrtz(res[cc][4], res[cc][5]));
          pv.w = __builtin_bit_cast(uint, __builtin_amdgcn_cvt_pkrtz(res[cc][6], res[cc][7]));
          res16[kb * 32 + (rowL ^ dq)] = pv;
        } else {
          const float* xp = xT + (row0 + rowL) * D_ + go;
          const float4 x0 = *(const float4*)xp, x1 = *(const float4*)(xp + 4);
          const float xf[8] = {x0.x, x0.y, x0.z, x0.w, x1.x, x1.y, x1.z, x1.w};
          float o[8];
#pragma unroll
          for (int j = 0; j < 8; ++j) o[j] = xf[j] - (res[cc][j] - wf[j]);
          float* od = out + (row0 + rowL) * D_ + go;
          *(float4*)od       = make_float4(o[0], o[1], o[2], o[3]);
          *(float4*)(od + 4) = make_float4(o[4], o[5], o[6], o[7]);
        }
      }
      if (dq == 0) {
        out[IDX_OFF + (size_t)s * (B_ * T_) + row0 + rowL] = (float)win;
        lossW = dwn;
      }
    }
    // lossW nonzero only on lanes with dq==0 (l % 8 == 0): masks 8/16/32 suffice
#pragma unroll
    for (int m = 8; m <= 32; m <<= 1) lossW += __shfl_xor(lossW, m);
    if (l == 0) atomicAdd(&lossbuf[s], lossW);
    __syncthreads();
  }
}

__global__ void rvq_loss(const double* __restrict__ lossbuf, float* __restrict__ out) {
  const int s = threadIdx.x;
  if (s < NQ_) out[LOSS_OFF + s] = (float)(2.0 * lossbuf[s] / (double)((size_t)B_ * T_ * D_));
}

extern "C" void kernel_launch(void* const* d_in, const int* in_sizes, int n_in,
                              void* d_out, int out_size, void* d_ws, size_t ws_size,
                              hipStream_t stream) {
  const float* x  = (const float*)d_in[0];   // [B, D, T] f32
  const float* cb = (const float*)d_in[1];   // [NQ, K, D] f32
  float* out = (float*)d_out;
  char* ws = (char*)d_ws;
  float*  xTp   = (float*)(ws + XT_OFF);
  ushort* cb16p = (ushort*)(ws + CB16_OFF);
  float*  cnp   = (float*)(ws + CN_OFF);
  double* lbp   = (double*)(ws + LB_OFF);

  hipMemsetAsync(ws + LB_OFF, 0, NQ_ * sizeof(double), stream);
  prep_xT<<<2048, 256, 0, stream>>>(x, xTp);
  prep_cb16<<<2048, 256, 0, stream>>>(cb, cb16p, cnp);
  rvq_main<<<1024, 256, 0, stream>>>(cb, xTp, cb16p, cnp, out, lbp);
  rvq_loss<<<1, 64, 0, stream>>>(lbp, out);
}

// Round 5
// 571.327 us; speedup vs baseline: 1.6238x; 1.0336x over previous
//
#include <hip/hip_runtime.h>

#define B_   8
#define D_   256
#define T_   4096
#define NQ_  8
#define K_   1024

#define IDX_OFF  ((size_t)B_ * T_ * D_)             // 8388608
#define LOSS_OFF (IDX_OFF + (size_t)NQ_ * B_ * T_)  // 8650752

// ---- workspace layout (bytes) ----
#define XT_OFF   0ull                      // float xT[32768][256] (32 MB)
#define CB16_OFF 33554432ull               // fp16 codebook in MFMA A-frag order (4 MB)
#define CN_OFF   37748736ull               // float cnorm[8192]
#define LB_OFF   37781504ull               // double lossbuf[8]

typedef _Float16 half8 __attribute__((ext_vector_type(8)));   // 4 VGPR MFMA frag
typedef float   f32x16 __attribute__((ext_vector_type(16)));  // MFMA C/D

__device__ __forceinline__ ushort f2h(float f) {
  return __builtin_bit_cast(ushort, (_Float16)f);
}

// packed score: low 10 mantissa bits replaced by code -> branch-free sorted-top-3
__device__ __forceinline__ float packsc(float sc, uint code) {
  return __builtin_bit_cast(float, (__builtin_bit_cast(uint, sc) & ~1023u) | code);
}
// sorted top-3 insert via min/max/med3 (4 VALU ops, dep depth 2)
__device__ __forceinline__ void ins3(float& v1, float& v2, float& v3, float f) {
  const float a = v1;
  const float m = fmaxf(v1, f);
  v1 = fminf(v1, f);
  const float v2n = __builtin_amdgcn_fmed3f(a, v2, f);
  v3 = __builtin_amdgcn_fmed3f(v2, v3, m);
  v2 = v2n;
}

// ---- prep 1: x [B,D,T] -> xT f32 [row=b*T+t][d] ----
__global__ void prep_xT(const float* __restrict__ x, float* __restrict__ xT) {
  __shared__ float tile[64][65];
  const int bidx = blockIdx.x;                 // 8 b * 4 dchunk * 64 tchunk
  const int b = bidx >> 8, dc = (bidx >> 6) & 3, tc = bidx & 63;
  const int d0 = dc * 64, t0 = tc * 64;
  const int tid = threadIdx.x;
  {
    const int tt = tid & 63, dg = tid >> 6;
    for (int i = 0; i < 16; ++i) {
      const int d = dg * 16 + i;
      tile[d][tt] = x[((size_t)(b * D_ + d0 + d)) * T_ + t0 + tt];
    }
  }
  __syncthreads();
  {
    const int dw = tid & 63, tg = tid >> 6;
    for (int i = 0; i < 16; ++i) {
      const int t = tg * 16 + i;
      xT[((size_t)b * T_ + t0 + t) * D_ + d0 + dw] = tile[dw][t];
    }
  }
}

// ---- prep 2: cb f32 -> fp16 MFMA A-frag order + f64-accurate cnorm (f32 out) ----
// layout: cb16[stage][tile(code>>5)][ks(k>>4)][lane][8]; lane = ((k>>3)&1)*32 + (code&31), j=k&7
__global__ void prep_cb16(const float* __restrict__ cb, ushort* __restrict__ cb16,
                          float* __restrict__ cnorm) {
  const int tid = threadIdx.x, w = tid >> 6, l = tid & 63;
  const int code = blockIdx.x * 4 + w;         // grid 2048
  const int s = code >> 10, ci = code & 1023, tile = ci >> 5, n = ci & 31;
  const float* row = cb + (size_t)code * D_;
  const float4 v = *(const float4*)(row + l * 4);
  double nrm = (double)v.x * v.x + (double)v.y * v.y + (double)v.z * v.z + (double)v.w * v.w;
  ushort4 p;
  p.x = f2h(v.x); p.y = f2h(v.y); p.z = f2h(v.z); p.w = f2h(v.w);
  const int ks = l >> 2, lf = ((l >> 1) & 1) * 32 + n, j0 = (l & 1) * 4;
  const size_t off = (((size_t)s * 32 + tile) * 16 + ks) * 512 + (size_t)lf * 8 + j0;
  *(ushort4*)(cb16 + off) = p;
#pragma unroll
  for (int m = 1; m <= 32; m <<= 1) nrm += __shfl_xor(nrm, m);
  if (l == 0) cnorm[code] = (float)nrm;
}

// ---- main: 512 blocks x 512 thr; block = 64 rows (2 row-groups of 32) ----
// Occupancy has been pinned at ~2 workgroups/CU across LDS 70->18KB and VGPR 64-88
// (rounds 0-4) -> the residency cap is per-WORKGROUP, not LDS/VGPR. So: 8 waves per
// workgroup. Waves 0-3 serve row-group 0 (rows 0-31), waves 4-7 serve row-group 1;
// within a group, wave ww handles codes ww*256..+255 (8 tiles). Everything else is
// the proven round-4 structure (B per-tile from LDS fp16 frag image, f32 residual in
// regs, f64 top-3 re-eval).
__global__ __launch_bounds__(512)
void rvq_main(const float* __restrict__ cb, const float* __restrict__ xT,
              const ushort* __restrict__ cb16, const float* __restrict__ cnorm,
              float* __restrict__ out, double* __restrict__ lossbuf) {
  __shared__ __align__(16) uint4  res16[2048];      // 32 KB fp16 residual, B-frag layout, 2 groups
  __shared__ float candm[64][12];                   // packed score|code, 3 KB

  const int tid = threadIdx.x;
  const int w = tid >> 6, l = tid & 63, n5 = l & 31, h = l >> 5;
  const int g = w >> 2, ww = w & 3;     // row-group, wave-within-group
  const size_t row0 = (size_t)blockIdx.x * 64;
  const int rowL = tid >> 3;            // phase-3 row (0..63)
  const int g3 = rowL >> 5;             // phase-3 row-group
  const int dq = tid & 7;               // phase-3 dim-octant (32 dims)

  float res[4][8];                      // f32 residual (reference arithmetic), register-resident

  // ---- init: residual = x; write fp16 frag image ----
  {
#pragma unroll
    for (int cc = 0; cc < 4; ++cc) {
      const int kb = dq * 4 + cc;
      const float* xp = xT + (row0 + rowL) * D_ + kb * 8;
      const float4 x0 = *(const float4*)xp, x1 = *(const float4*)(xp + 4);
      res[cc][0] = x0.x; res[cc][1] = x0.y; res[cc][2] = x0.z; res[cc][3] = x0.w;
      res[cc][4] = x1.x; res[cc][5] = x1.y; res[cc][6] = x1.z; res[cc][7] = x1.w;
      uint4 pv;
      pv.x = __builtin_bit_cast(uint, __builtin_amdgcn_cvt_pkrtz(x0.x, x0.y));
      pv.y = __builtin_bit_cast(uint, __builtin_amdgcn_cvt_pkrtz(x0.z, x0.w));
      pv.z = __builtin_bit_cast(uint, __builtin_amdgcn_cvt_pkrtz(x1.x, x1.y));
      pv.w = __builtin_bit_cast(uint, __builtin_amdgcn_cvt_pkrtz(x1.z, x1.w));
      res16[g3 * 1024 + kb * 32 + ((rowL & 31) ^ dq)] = pv;   // (kb>>2)&7 == dq
    }
  }
  __syncthreads();

  for (int s = 0; s < NQ_; ++s) {
    // ===== K-loop: 8 tiles; per tile 16 A global-loads + 16 B lds-reads + 16 MFMAs =====
    float v1 = 3e38f, v2 = 3e38f, v3 = 3e38f;   // chain A
    float u1 = 3e38f, u2 = 3e38f, u3 = 3e38f;   // chain B
    for (int tt = 0; tt < 8; ++tt) {
      const int t = ww * 8 + tt;
      const uint4* ap = (const uint4*)(cb16 + ((size_t)(s * 32 + t) * 16) * 512) + l;
      int zr = 0;
      asm volatile("" : "+v"(zr));               // opaque 0: B addresses not loop-invariant
      const uint4* bp = res16 + g * 1024 + zr;
      f32x16 acc;
#pragma unroll
      for (int r = 0; r < 16; ++r) acc[r] = 0.0f;
#pragma unroll
      for (int q = 0; q < 4; ++q) {              // 4-chunks bound transient reg pressure
        uint4 av[4], bv[4];
#pragma unroll
        for (int c = 0; c < 4; ++c) {
          const int ks = q * 4 + c;
          av[c] = ap[(size_t)ks * 64];
          bv[c] = bp[(ks * 2 + h) * 32 + (n5 ^ ((ks >> 1) & 7))];
        }
#pragma unroll
        for (int c = 0; c < 4; ++c) {
          acc = __builtin_amdgcn_mfma_f32_32x32x16_f16(
              __builtin_bit_cast(half8, av[c]), __builtin_bit_cast(half8, bv[c]), acc, 0, 0, 0);
        }
      }
      const float* cnb = cnorm + s * K_ + t * 32 + h * 4;
      const uint cbase = (uint)(t * 32 + 4 * h);
#pragma unroll
      for (int q = 0; q < 4; ++q) {                      // quarter-split keeps cna regs low
        const float4 cq = *(const float4*)(cnb + q * 8);
        const float cna[4] = {cq.x, cq.y, cq.z, cq.w};
#pragma unroll
        for (int rr = 0; rr < 4; ++rr) {
          const int r = q * 4 + rr;
          const float sc = cna[rr] - 2.0f * acc[r];
          const uint code = cbase + (uint)(8 * q + rr);  // == t*32 + (r&3) + 8*(r>>2) + 4*h
          const float f = packsc(sc, code);
          if (rr & 1) ins3(u1, u2, u3, f);
          else        ins3(v1, v2, v3, f);
        }
      }
    }
    // merge chain B into chain A
    ins3(v1, v2, v3, u1);
    ins3(v1, v2, v3, u2);
    ins3(v1, v2, v3, u3);
    // merge h-halves (lane l <-> l^32, same x-row, disjoint codes)
    {
      const float o1 = __shfl_xor(v1, 32), o2 = __shfl_xor(v2, 32), o3 = __shfl_xor(v3, 32);
      ins3(v1, v2, v3, o1);
      ins3(v1, v2, v3, o2);
      ins3(v1, v2, v3, o3);
    }
    if (h == 0) {
      candm[g * 32 + n5][ww * 3 + 0] = v1;
      candm[g * 32 + n5][ww * 3 + 1] = v2;
      candm[g * 32 + n5][ww * 3 + 2] = v3;
    }
    __syncthreads();   // all K-loop res16 reads done before phase-3 rewrites

    // ===== phase 3: 8 lanes/row x 32 dims; f64 re-eval of top-3-of-12 (f32 residual) =====
    double lossW = 0.0;
    {
      float m1 = 3e38f, m2 = 3e38f, m3 = 3e38f;
#pragma unroll
      for (int cd = 0; cd < 12; ++cd) ins3(m1, m2, m3, candm[rowL][cd]);
      const int c1 = (int)(__builtin_bit_cast(uint, m1) & 1023u);
      const int c2 = (int)(__builtin_bit_cast(uint, m2) & 1023u);
      const int c3 = (int)(__builtin_bit_cast(uint, m3) & 1023u);

      const float* cbs = cb + (size_t)s * K_ * D_;
      const float* cr0 = cbs + (size_t)c1 * D_;
      const float* cr1 = cbs + (size_t)c2 * D_;
      const float* cr2 = cbs + (size_t)c3 * D_;
      double dd0 = 0.0, dd1 = 0.0, dd2 = 0.0;
#pragma unroll
      for (int cc = 0; cc < 4; ++cc) {
        const int kb = dq * 4 + cc;
        const int go = kb * 8;
        const float4 a0 = *(const float4*)(cr0 + go), a1 = *(const float4*)(cr0 + go + 4);
        const float4 b0 = *(const float4*)(cr1 + go), b1 = *(const float4*)(cr1 + go + 4);
        const float4 g0 = *(const float4*)(cr2 + go), g1 = *(const float4*)(cr2 + go + 4);
        const float af[8] = {a0.x, a0.y, a0.z, a0.w, a1.x, a1.y, a1.z, a1.w};
        const float bf[8] = {b0.x, b0.y, b0.z, b0.w, b1.x, b1.y, b1.z, b1.w};
        const float gf[8] = {g0.x, g0.y, g0.z, g0.w, g1.x, g1.y, g1.z, g1.w};
#pragma unroll
        for (int j = 0; j < 8; ++j) {
          const double r64 = (double)res[cc][j];
          const double u = r64 - (double)af[j]; dd0 += u * u;
          const double v = r64 - (double)bf[j]; dd1 += v * v;
          const double gg = r64 - (double)gf[j]; dd2 += gg * gg;
        }
      }
#pragma unroll
      for (int m = 1; m <= 4; m <<= 1) {
        dd0 += __shfl_xor(dd0, m); dd1 += __shfl_xor(dd1, m); dd2 += __shfl_xor(dd2, m);
      }
      int win = c1; double dwn = dd0;
      if (dd1 < dwn || (dd1 == dwn && c2 < win)) { win = c2; dwn = dd1; }
      if (dd2 < dwn || (dd2 == dwn && c3 < win)) { win = c3; dwn = dd2; }
      const float* crw = cbs + (size_t)win * D_;
#pragma unroll
      for (int cc = 0; cc < 4; ++cc) {
        const int kb = dq * 4 + cc;
        const int go = kb * 8;
        const float4 w0 = *(const float4*)(crw + go), w1 = *(const float4*)(crw + go + 4);
        const float wf[8] = {w0.x, w0.y, w0.z, w0.w, w1.x, w1.y, w1.z, w1.w};
        if (s < NQ_ - 1) {
#pragma unroll
          for (int j = 0; j < 8; ++j) res[cc][j] = res[cc][j] - wf[j];   // f32: matches reference
          uint4 pv;
          pv.x = __builtin_bit_cast(uint, __builtin_amdgcn_cvt_pkrtz(res[cc][0], res[cc][1]));
          pv.y = __builtin_bit_cast(uint, __builtin_amdgcn_cvt_pkrtz(res[cc][2], res[cc][3]));
          pv.z = __builtin_bit_cast(uint, __builtin_amdgcn_cvt_pkrtz(res[cc][4], res[cc][5]));
          pv.w = __builtin_bit_cast(uint, __builtin_amdgcn_cvt_pkrtz(res[cc][6], res[cc][7]));
          res16[g3 * 1024 + kb * 32 + ((rowL & 31) ^ dq)] = pv;
        } else {
          const float* xp = xT + (row0 + rowL) * D_ + go;
          const float4 x0 = *(const float4*)xp, x1 = *(const float4*)(xp + 4);
          const float xf[8] = {x0.x, x0.y, x0.z, x0.w, x1.x, x1.y, x1.z, x1.w};
          float o[8];
#pragma unroll
          for (int j = 0; j < 8; ++j) o[j] = xf[j] - (res[cc][j] - wf[j]);
          float* od = out + (row0 + rowL) * D_ + go;
          *(float4*)od       = make_float4(o[0], o[1], o[2], o[3]);
          *(float4*)(od + 4) = make_float4(o[4], o[5], o[6], o[7]);
        }
      }
      if (dq == 0) {
        out[IDX_OFF + (size_t)s * (B_ * T_) + row0 + rowL] = (float)win;
        lossW = dwn;
      }
    }
    // lossW nonzero only on lanes with dq==0 (l % 8 == 0): masks 8/16/32 suffice
#pragma unroll
    for (int m = 8; m <= 32; m <<= 1) lossW += __shfl_xor(lossW, m);
    if (l == 0) atomicAdd(&lossbuf[s], lossW);
    __syncthreads();
  }
}

__global__ void rvq_loss(const double* __restrict__ lossbuf, float* __restrict__ out) {
  const int s = threadIdx.x;
  if (s < NQ_) out[LOSS_OFF + s] = (float)(2.0 * lossbuf[s] / (double)((size_t)B_ * T_ * D_));
}

extern "C" void kernel_launch(void* const* d_in, const int* in_sizes, int n_in,
                              void* d_out, int out_size, void* d_ws, size_t ws_size,
                              hipStream_t stream) {
  const float* x  = (const float*)d_in[0];   // [B, D, T] f32
  const float* cb = (const float*)d_in[1];   // [NQ, K, D] f32
  float* out = (float*)d_out;
  char* ws = (char*)d_ws;
  float*  xTp   = (float*)(ws + XT_OFF);
  ushort* cb16p = (ushort*)(ws + CB16_OFF);
  float*  cnp   = (float*)(ws + CN_OFF);
  double* lbp   = (double*)(ws + LB_OFF);

  hipMemsetAsync(ws + LB_OFF, 0, NQ_ * sizeof(double), stream);
  prep_xT<<<2048, 256, 0, stream>>>(x, xTp);
  prep_cb16<<<2048, 256, 0, stream>>>(cb, cb16p, cnp);
  rvq_main<<<512, 512, 0, stream>>>(cb, xTp, cb16p, cnp, out, lbp);
  rvq_loss<<<1, 64, 0, stream>>>(lbp, out);
}